// Round 5
// baseline (408.966 us; speedup 1.0000x reference)
//
#include <hip/hip_runtime.h>

typedef unsigned short u16;
typedef u16   u16x4  __attribute__((ext_vector_type(4)));
typedef u16   u16x8  __attribute__((ext_vector_type(8)));
typedef __bf16 bf16x8 __attribute__((ext_vector_type(8)));
typedef float f32x4  __attribute__((ext_vector_type(4)));

constexpr int BATCH  = 4;
constexpr int CDIM   = 256;
constexpr int NTOK   = 16384;   // 128*128
constexpr int INNERD = 512;

// native bf16 converts (v_cvt_pk_bf16_f32, RNE)
__device__ __forceinline__ u16 f2b(float f) {
  return __builtin_bit_cast(u16, (__bf16)f);
}
__device__ __forceinline__ float b2f(u16 b) {
  return (float)__builtin_bit_cast(__bf16, b);
}

// async global->LDS, 16B per lane. LDS dest must be WAVE-UNIFORM base;
// HW writes lane i's data at base + i*16. Global src is per-lane.
__device__ __forceinline__ void async_ld16(const u16* g, u16* l) {
  __builtin_amdgcn_global_load_lds(
      (const __attribute__((address_space(1))) void*)g,
      (__attribute__((address_space(3))) void*)l, 16, 0, 0);
}

// ---------------- transpose + convert: (b,c,n) fp32 -> (b,n,c) bf16 -------------
// 64x64 tiles, float4 global reads (G13: 4x fewer VMEM insts than scalar).
__global__ __launch_bounds__(256) void transpose_cvt(
    const float* __restrict__ x, const float* __restrict__ ctx,
    u16* __restrict__ xt, u16* __restrict__ ct) {
  __shared__ __align__(16) float tile[64][68];   // 68: 272B row, 16B-aligned, pad vs banks
  int zb = blockIdx.z;            // 0..7 : b*2 + which
  int b = zb >> 1;
  const float* src = (zb & 1) ? ctx : x;
  u16* dst = (zb & 1) ? ct : xt;
  src += (size_t)b * CDIM * NTOK;
  dst += (size_t)b * NTOK * CDIM;
  int n0 = blockIdx.x * 64, c0 = blockIdx.y * 64;
  int tx = threadIdx.x & 15, ty = threadIdx.x >> 4;   // ty 0..15
#pragma unroll
  for (int i = 0; i < 64; i += 16) {
    f32x4 v = *(const f32x4*)&src[(size_t)(c0 + ty + i) * NTOK + n0 + tx * 4];
    *(f32x4*)&tile[ty + i][tx * 4] = v;
  }
  __syncthreads();
  int nl = threadIdx.x >> 3;          // 0..31
  int cl = (threadIdx.x & 7) * 8;     // 0..56
#pragma unroll
  for (int j2 = 0; j2 < 2; j2++) {
    int nn = nl + 32 * j2;
    u16x8 o;
#pragma unroll
    for (int j = 0; j < 8; j++) o[j] = f2b(tile[cl + j][nn]);
    *(u16x8*)&dst[(size_t)(n0 + nn) * CDIM + c0 + cl] = o;
  }
}

// ---------------- weight transpose: (256,512) fp32 -> (512,256) bf16 ------------
__global__ __launch_bounds__(256) void wtrans(
    const float* __restrict__ Wq, const float* __restrict__ Wk, const float* __restrict__ Wv,
    u16* __restrict__ qt, u16* __restrict__ kt, u16* __restrict__ vt) {
  __shared__ float tile[32][33];
  const float* src = blockIdx.z == 0 ? Wq : (blockIdx.z == 1 ? Wk : Wv);
  u16* dst = blockIdx.z == 0 ? qt : (blockIdx.z == 1 ? kt : vt);
  int i0 = blockIdx.x * 32, c0 = blockIdx.y * 32;
  int tx = threadIdx.x & 31, ty = threadIdx.x >> 5;
#pragma unroll
  for (int r = 0; r < 32; r += 8)
    tile[ty + r][tx] = src[(size_t)(c0 + ty + r) * INNERD + i0 + tx];
  __syncthreads();
#pragma unroll
  for (int r = 0; r < 32; r += 8)
    dst[(size_t)(i0 + ty + r) * CDIM + c0 + tx] = f2b(tile[tx][ty + r]);
}

// ---------------- zero scratch -------------------------------------------------
__global__ void zero_f32(float* p, int nelem) {
  int i = blockIdx.x * blockDim.x + threadIdx.x;
  if (i < nelem) p[i] = 0.0f;
}

// ================= fused projection + context matrix ===========================
// Per block: b, i-range 128 (heads ig*2, ig*2+1), n-chunk 512.
// MERGED K/V ladder: per 128-n tile, ONE k0 loop stages {Wk,Wv,ctx} (ctx staged
// once, not twice) and accumulates acc_k + acc_v together (64 MFMA per k-step
// per wave -> better stall hiding; barriers per nt 18 -> 10). Then exp->Ek,
// Vt (aliases staging), cm MFMA with ksum via ones-operand. Atomics epilogue.
__global__ __launch_bounds__(256, 2) void proj_ctx(
    const u16* __restrict__ Wkt, const u16* __restrict__ Wvt,
    const u16* __restrict__ ctx_bt, float* __restrict__ cm, float* __restrict__ ksum) {
  // 512 blocks = 4(ig) x 32(nc) x 4(b); chunked XCD swizzle: XCD gets 64
  // consecutive swz -> ig fastest (4 siblings share the ctx slice in L2).
  int id = blockIdx.x;
  int swz = (id & 7) * 64 + (id >> 3);
  int ig = swz & 3, nc = (swz >> 2) & 31, b = swz >> 7;
  int i0 = ig * 128;
  const u16* Bt = ctx_bt + (size_t)b * NTOK * CDIM;

  __shared__ __align__(16) u16 smem[40960];   // 80 KiB -> 2 blocks/CU
  u16* Ask = smem;            // [0,16K)    K-weight staging
  u16* Asv = smem + 8192;     // [16K,32K)  V-weight staging
  u16* Bs  = smem + 16384;    // [32K,48K)  ctx staging
  u16* Vt  = smem;            // [0,32K)    V tile, aliases Ask+Asv
  u16* Ek  = smem + 24576;    // [48K,80K)  expK tile, dedicated

  int tid = threadIdx.x, wave = tid >> 6, lane = tid & 63;
  int wm = (wave >> 1) * 64, wn = (wave & 1) * 64;
  int quad = lane >> 4, l16 = lane & 15;
  int srow = lane >> 3, scol = (lane & 7) * 8;

  int hl = wave >> 1, dblk = (wave & 1) * 32;   // phase-2: wave -> (head, d-half)

  u16x8 ov;
#pragma unroll
  for (int t = 0; t < 8; t++) ov[t] = 0x3f80;   // bf16 1.0
  const bf16x8 ones = __builtin_bit_cast(bf16x8, ov);

  f32x4 acc_cm[2][4];
  f32x4 accS[2];
#pragma unroll
  for (int i = 0; i < 2; i++) {
    accS[i] = (f32x4)(0.0f);
#pragma unroll
    for (int j = 0; j < 4; j++) acc_cm[i][j] = (f32x4)(0.0f);
  }

  for (int nt = 0; nt < 4; nt++) {
    int n0 = nc * 512 + nt * 128;
    f32x4 acc_k[4][4], acc_v[4][4];
#pragma unroll
    for (int i = 0; i < 4; i++)
#pragma unroll
      for (int j = 0; j < 4; j++) { acc_k[i][j] = (f32x4)(0.0f); acc_v[i][j] = (f32x4)(0.0f); }

    for (int k0 = 0; k0 < CDIM; k0 += 64) {
      __syncthreads();                 // prev reads of staging (or Vt/Ek) done
#pragma unroll
      for (int j = 0; j < 12; j++) {   // 48 x 1KiB chunks, 12 per wave
        int buf = j >> 2;              // 0=Ask 1=Asv 2=Bs
        int tc  = wave * 4 + (j & 3);  // 0..15
        int row = tc * 8 + srow;
        const u16* g = buf == 0 ? &Wkt[(size_t)(i0 + row) * CDIM + k0 + scol]
                     : buf == 1 ? &Wvt[(size_t)(i0 + row) * CDIM + k0 + scol]
                                : &Bt [(size_t)(n0 + row) * CDIM + k0 + scol];
        async_ld16(g, smem + buf * 8192 + tc * 512);
      }
      __syncthreads();                 // drains vmcnt(0)
#pragma unroll
      for (int kk = 0; kk < 64; kk += 32) {
        int ko = kk + quad * 8;
        bf16x8 ak[4], av[4], bfr[4];
#pragma unroll
        for (int m = 0; m < 4; m++) {
          ak[m] = __builtin_bit_cast(bf16x8, *(const u16x8*)&Ask[(wm + m * 16 + l16) * 64 + ko]);
          av[m] = __builtin_bit_cast(bf16x8, *(const u16x8*)&Asv[(wm + m * 16 + l16) * 64 + ko]);
        }
#pragma unroll
        for (int e = 0; e < 4; e++)
          bfr[e] = __builtin_bit_cast(bf16x8, *(const u16x8*)&Bs[(wn + e * 16 + l16) * 64 + ko]);
        // swapped operands: lane holds 4 consecutive n per frag
#pragma unroll
        for (int e = 0; e < 4; e++)
#pragma unroll
          for (int m = 0; m < 4; m++) {
            acc_k[e][m] = __builtin_amdgcn_mfma_f32_16x16x32_bf16(bfr[e], ak[m], acc_k[e][m], 0, 0, 0);
            acc_v[e][m] = __builtin_amdgcn_mfma_f32_16x16x32_bf16(bfr[e], av[m], acc_v[e][m], 0, 0, 0);
          }
      }
    }
    __syncthreads();                   // all staging reads done (Vt aliases it)
    // write tiles to LDS, XOR-swizzled: byte ^= (row&7)<<4  (2-way max on r/w)
#pragma unroll
    for (int e = 0; e < 4; e++) {
      int nl0 = wn + e * 16 + quad * 4;
#pragma unroll
      for (int m = 0; m < 4; m++) {
        int row = wm + m * 16 + l16;   // i-local 0..127
        u16x4 ok, ovv;
#pragma unroll
        for (int r = 0; r < 4; r++) {
          ok[r]  = f2b(__expf(acc_k[e][m][r]));
          ovv[r] = f2b(acc_v[e][m][r]);
        }
        unsigned byt = (unsigned)(row * 256 + nl0 * 2) ^ ((unsigned)(row & 7) << 4);
        *(u16x4*)((char*)Ek + byt) = ok;
        *(u16x4*)((char*)Vt + byt) = ovv;
      }
    }
    __syncthreads();                   // Ek/Vt visible to all waves
    // phase 2: per wave (hl, dblk): acc_cm[m2][e2] += Ek_row · Vt_row over 128 n
#pragma unroll
    for (int kk = 0; kk < 128; kk += 32) {
      int ko = kk + quad * 8;
      bf16x8 ea[2], vb[4];
#pragma unroll
      for (int m2 = 0; m2 < 2; m2++) {
        int row = hl * 64 + dblk + m2 * 16 + l16;
        unsigned byt = (unsigned)(row * 256 + ko * 2) ^ ((unsigned)(row & 7) << 4);
        ea[m2] = __builtin_bit_cast(bf16x8, *(const u16x8*)((char*)Ek + byt));
      }
#pragma unroll
      for (int e2 = 0; e2 < 4; e2++) {
        int row = hl * 64 + e2 * 16 + l16;
        unsigned byt = (unsigned)(row * 256 + ko * 2) ^ ((unsigned)(row & 7) << 4);
        vb[e2] = __builtin_bit_cast(bf16x8, *(const u16x8*)((char*)Vt + byt));
      }
#pragma unroll
      for (int m2 = 0; m2 < 2; m2++) {
        accS[m2] = __builtin_amdgcn_mfma_f32_16x16x32_bf16(ea[m2], ones, accS[m2], 0, 0, 0);
#pragma unroll
        for (int e2 = 0; e2 < 4; e2++)
          acc_cm[m2][e2] = __builtin_amdgcn_mfma_f32_16x16x32_bf16(ea[m2], vb[e2], acc_cm[m2][e2], 0, 0, 0);
      }
    }
    // next nt's first __syncthreads protects Ek/Vt vs staging overwrite
  }
  // epilogue: waves own disjoint (h, d-half) -> no intra-block contention
  int h = ig * 2 + hl;
  float* cmp = cm + (size_t)(b * 8 + h) * 64 * 64;
#pragma unroll
  for (int m2 = 0; m2 < 2; m2++)
#pragma unroll
    for (int e2 = 0; e2 < 4; e2++)
#pragma unroll
      for (int r = 0; r < 4; r++) {
        int d = dblk + m2 * 16 + quad * 4 + r;
        int e = e2 * 16 + l16;
        atomicAdd(&cmp[d * 64 + e], acc_cm[m2][e2][r]);
      }
  if (l16 == 0) {
#pragma unroll
    for (int m2 = 0; m2 < 2; m2++)
#pragma unroll
      for (int r = 0; r < 4; r++) {
        int d = dblk + m2 * 16 + quad * 4 + r;
        atomicAdd(&ksum[(size_t)b * INNERD + h * 64 + d], accS[m2][r]);
      }
  }
}

// ---------------- weff[b][i=h*64+d][c] = (sum_e cm[d][e]*Wo[h*64+e][c])/ksum ---
__global__ __launch_bounds__(256) void weff_k(
    const float* __restrict__ cm, const float* __restrict__ Wo,
    const float* __restrict__ ksum, float* __restrict__ weff) {
  int bi = blockIdx.x;            // 0..2047
  int b = bi >> 9, i = bi & 511, h = i >> 6, d = i & 63;
  const float* cmr = cm + ((size_t)(b * 8 + h) * 64 + d) * 64;
  __shared__ float cs[64];
  if (threadIdx.x < 64) cs[threadIdx.x] = cmr[threadIdx.x];
  __syncthreads();
  float inv = 1.0f / ksum[(size_t)b * INNERD + i];
  int c = threadIdx.x;
  float s = 0.0f;
#pragma unroll 8
  for (int e = 0; e < 64; e++) s += cs[e] * Wo[(size_t)(h * 64 + e) * CDIM + c];
  weff[(size_t)bi * CDIM + c] = s * inv;
}

// ---------------- Gt[b][c][c'] = sum_i weff[b][i][c] * Wq_t[i][c']  (bf16) -----
__global__ __launch_bounds__(256) void gt_k(
    const float* __restrict__ weff, const u16* __restrict__ Wq_t, u16* __restrict__ Gt) {
  int bc = blockIdx.x;            // 0..1023
  int b = bc >> 8, c = bc & 255;
  __shared__ float ws[512];
  for (int j = threadIdx.x; j < 512; j += 256)
    ws[j] = weff[((size_t)b * 512 + j) * CDIM + c];
  __syncthreads();
  int cp = threadIdx.x;
  float s = 0.0f;
#pragma unroll 8
  for (int i = 0; i < 512; i++) s += ws[i] * b2f(Wq_t[(size_t)i * CDIM + cp]);
  Gt[(size_t)bc * CDIM + cp] = f2b(s);
}

// ---------------- final: out[b][c][n] = x + bo[c] + sum_c' Gt[c][c'] x_bt[n][c']
// SWAPPED operands: lane holds 4 consecutive n -> float4 load of x, float4 store.
__global__ __launch_bounds__(256) void final_gemm(
    const u16* __restrict__ Gt, const u16* __restrict__ x_bt,
    const float* __restrict__ x, const float* __restrict__ bo,
    float* __restrict__ out) {
  // flattened grid 1024 = 2(x) * 128(y) * 4(z); chunked XCD swizzle
  int id = blockIdx.x;
  int swz = (id & 7) * 128 + (id >> 3);
  int bx = swz & 1, by = (swz >> 1) & 127, b = swz >> 8;
  const u16* A  = Gt + (size_t)b * CDIM * CDIM;
  const u16* Bt = x_bt + (size_t)b * NTOK * CDIM;
  const float* xb = x + (size_t)b * CDIM * NTOK;
  float* ob = out + (size_t)b * CDIM * NTOK;
  int i0 = bx * 128;
  int n0 = by * 128;

  __shared__ __align__(16) u16 As[128 * 64];
  __shared__ __align__(16) u16 Bs[128 * 64];

  int tid = threadIdx.x;
  int wave = tid >> 6, lane = tid & 63;
  int wm = (wave >> 1) * 64, wn = (wave & 1) * 64;
  int quad = lane >> 4, l16 = lane & 15;
  int srow = lane >> 3, scol = (lane & 7) * 8;

  f32x4 acc[4][4];   // [e:n-frag][m:c-frag]
#pragma unroll
  for (int i = 0; i < 4; i++)
#pragma unroll
    for (int j = 0; j < 4; j++) acc[i][j] = (f32x4)(0.0f);

  for (int k0 = 0; k0 < CDIM; k0 += 64) {
    __syncthreads();
#pragma unroll
    for (int j = 0; j < 4; j++) {
      int t = wave * 4 + j;
      int row = t * 8 + srow;
      async_ld16(&A [(size_t)(i0 + row) * CDIM + k0 + scol], &As[t * 512]);
      async_ld16(&Bt[(size_t)(n0 + row) * CDIM + k0 + scol], &Bs[t * 512]);
    }
    __syncthreads();
#pragma unroll
    for (int kk = 0; kk < 64; kk += 32) {
      int ko = kk + quad * 8;
      bf16x8 af[4], bfr[4];
#pragma unroll
      for (int m = 0; m < 4; m++)
        af[m] = __builtin_bit_cast(bf16x8, *(const u16x8*)&As[(wm + m * 16 + l16) * 64 + ko]);
#pragma unroll
      for (int e = 0; e < 4; e++)
        bfr[e] = __builtin_bit_cast(bf16x8, *(const u16x8*)&Bs[(wn + e * 16 + l16) * 64 + ko]);
#pragma unroll
      for (int e = 0; e < 4; e++)
#pragma unroll
        for (int m = 0; m < 4; m++)
          acc[e][m] = __builtin_amdgcn_mfma_f32_16x16x32_bf16(bfr[e], af[m], acc[e][m], 0, 0, 0);
    }
  }
  // lane's acc[e][m][r]: c = i0+wm+m*16+l16, n = n0+wn+e*16+quad*4+r
#pragma unroll
  for (int e = 0; e < 4; e++) {
    int nb = n0 + wn + e * 16 + quad * 4;
#pragma unroll
    for (int m = 0; m < 4; m++) {
      int c = i0 + wm + m * 16 + l16;
      f32x4 xv = *(const f32x4*)&xb[(size_t)c * NTOK + nb];
      f32x4 r;
      float bc = bo[c];
#pragma unroll
      for (int t = 0; t < 4; t++) r[t] = acc[e][m][t] + xv[t] + bc;
      *(f32x4*)&ob[(size_t)c * NTOK + nb] = r;
    }
  }
}

extern "C" void kernel_launch(void* const* d_in, const int* in_sizes, int n_in,
                              void* d_out, int out_size, void* d_ws, size_t ws_size,
                              hipStream_t stream) {
  const float* x   = (const float*)d_in[0];
  const float* ctx = (const float*)d_in[1];
  const float* Wq  = (const float*)d_in[2];
  const float* Wk  = (const float*)d_in[3];
  const float* Wv  = (const float*)d_in[4];
  const float* Wo  = (const float*)d_in[5];
  const float* bo  = (const float*)d_in[6];
  float* out = (float*)d_out;

  char* ws = (char*)d_ws;
  u16* ctx_bt = (u16*)ws;  ws += (size_t)BATCH * NTOK * CDIM * 2;     // 32 MiB
  u16* x_bt   = (u16*)ws;  ws += (size_t)BATCH * NTOK * CDIM * 2;     // 32 MiB
  u16* Wq_t   = (u16*)ws;  ws += (size_t)INNERD * CDIM * 2;
  u16* Wk_t   = (u16*)ws;  ws += (size_t)INNERD * CDIM * 2;
  u16* Wv_t   = (u16*)ws;  ws += (size_t)INNERD * CDIM * 2;
  float* cm   = (float*)ws; ws += (size_t)BATCH * 8 * 64 * 64 * 4;    // 512 KiB
  float* ksum = (float*)ws; ws += (size_t)BATCH * INNERD * 4;         // 8 KiB (contiguous after cm)
  float* weff = (float*)ws; ws += (size_t)BATCH * INNERD * CDIM * 4;  // 2 MiB
  u16* Gt     = (u16*)ws;  ws += (size_t)BATCH * CDIM * CDIM * 2;

  const int nzero = BATCH * 8 * 64 * 64 + BATCH * INNERD;  // cm + ksum

  transpose_cvt<<<dim3(NTOK / 64, CDIM / 64, BATCH * 2), 256, 0, stream>>>(x, ctx, x_bt, ctx_bt);
  wtrans<<<dim3(INNERD / 32, CDIM / 32, 3), 256, 0, stream>>>(Wq, Wk, Wv, Wq_t, Wk_t, Wv_t);
  zero_f32<<<(nzero + 255) / 256, 256, 0, stream>>>(cm, nzero);
  proj_ctx<<<dim3(512), 256, 0, stream>>>(Wk_t, Wv_t, ctx_bt, cm, ksum);
  weff_k<<<BATCH * INNERD, 256, 0, stream>>>(cm, Wo, ksum, weff);
  gt_k<<<BATCH * CDIM, 256, 0, stream>>>(weff, Wq_t, Gt);
  final_gemm<<<dim3(1024), 256, 0, stream>>>(Gt, x_bt, x, bo, out);
}

// Round 7
// 306.674 us; speedup vs baseline: 1.3336x; 1.3336x over previous
//
#include <hip/hip_runtime.h>

typedef unsigned short u16;
typedef u16   u16x4  __attribute__((ext_vector_type(4)));
typedef u16   u16x8  __attribute__((ext_vector_type(8)));
typedef __bf16 bf16x8 __attribute__((ext_vector_type(8)));
typedef float f32x4  __attribute__((ext_vector_type(4)));

constexpr int BATCH  = 4;
constexpr int CDIM   = 256;
constexpr int NTOK   = 16384;   // 128*128
constexpr int INNERD = 512;

// native bf16 converts (v_cvt_pk_bf16_f32, RNE)
__device__ __forceinline__ u16 f2b(float f) {
  return __builtin_bit_cast(u16, (__bf16)f);
}
__device__ __forceinline__ float b2f(u16 b) {
  return (float)__builtin_bit_cast(__bf16, b);
}

// async global->LDS, 16B per lane. LDS dest must be WAVE-UNIFORM base;
// HW writes lane i's data at base + i*16. Global src is per-lane.
__device__ __forceinline__ void async_ld16(const u16* g, u16* l) {
  __builtin_amdgcn_global_load_lds(
      (const __attribute__((address_space(1))) void*)g,
      (__attribute__((address_space(3))) void*)l, 16, 0, 0);
}

// ---------------- prep: transpose_cvt + wtrans + zero fused (launch saving) ----
// id [0,16384): transpose (b,c,n) f32 -> (b,n,c) bf16 for x and ctx
// id [16384,16768): weight transpose (256,512) f32 -> (512,256) bf16
// id [16768,17288): zero cm/ksum scratch
constexpr int ZERO_N = BATCH * 8 * 64 * 64 + BATCH * INNERD;  // 133120
__global__ __launch_bounds__(256) void prep(
    const float* __restrict__ x, const float* __restrict__ ctx,
    const float* __restrict__ Wq, const float* __restrict__ Wk, const float* __restrict__ Wv,
    u16* __restrict__ xt, u16* __restrict__ ct,
    u16* __restrict__ qt, u16* __restrict__ kt, u16* __restrict__ vt,
    float* __restrict__ zbuf) {
  __shared__ float tile[64][33];   // reused by both transpose branches
  int id = blockIdx.x;
  if (id < 16384) {
    int bx = id & 511, by = (id >> 9) & 3, zb = id >> 11;
    int b = zb >> 1;
    const float* src = (zb & 1) ? ctx : x;
    u16* dst = (zb & 1) ? ct : xt;
    src += (size_t)b * CDIM * NTOK;
    dst += (size_t)b * NTOK * CDIM;
    int n0 = bx * 32, c0 = by * 64;
    int tx = threadIdx.x & 31, ty = threadIdx.x >> 5;   // ty 0..7
#pragma unroll
    for (int i = 0; i < 64; i += 8)
      tile[ty + i][tx] = src[(size_t)(c0 + ty + i) * NTOK + n0 + tx];
    __syncthreads();
    int nl = threadIdx.x >> 3;          // 0..31
    int cl = (threadIdx.x & 7) * 8;     // 0..56
    u16x8 o;
#pragma unroll
    for (int j = 0; j < 8; j++) o[j] = f2b(tile[cl + j][nl]);
    *(u16x8*)&dst[(size_t)(n0 + nl) * CDIM + c0 + cl] = o;
  } else if (id < 16768) {
    int idw = id - 16384;
    int bx = idw & 15, by = (idw >> 4) & 7, bz = idw >> 7;  // 16 x 8 x 3
    float (*t2)[33] = (float(*)[33])tile;
    const float* src = bz == 0 ? Wq : (bz == 1 ? Wk : Wv);
    u16* dst = bz == 0 ? qt : (bz == 1 ? kt : vt);
    int i0 = bx * 32, c0 = by * 32;
    int tx = threadIdx.x & 31, ty = threadIdx.x >> 5;
#pragma unroll
    for (int r = 0; r < 32; r += 8)
      t2[ty + r][tx] = src[(size_t)(c0 + ty + r) * INNERD + i0 + tx];
    __syncthreads();
#pragma unroll
    for (int r = 0; r < 32; r += 8)
      dst[(size_t)(i0 + ty + r) * CDIM + c0 + tx] = f2b(t2[tx][ty + r]);
  } else {
    int i = (id - 16768) * 256 + threadIdx.x;
    if (i < ZERO_N) zbuf[i] = 0.0f;
  }
}

// ================= fused projection + context matrix (prefetch ladder) =========
// Per block: b, i-range 128 (heads ig*2, ig*2+1), n-chunk 512.
// Round-4 memory map + sequential K->V (spill-free: one GEMM acc live at a time).
// BK=32 double-buffered staging with STAGE(next) issued BEFORE compute and
// ONE barrier per step (T3-minimum prefetch, m248 pattern) -> HBM latency hides
// under the 16 MFMA + frag reads instead of a full vmcnt(0) drain per step.
__global__ __launch_bounds__(256, 2) void proj_ctx(
    const u16* __restrict__ Wkt, const u16* __restrict__ Wvt,
    const u16* __restrict__ ctx_bt, float* __restrict__ cm, float* __restrict__ ksum) {
  // 512 blocks = 4(ig) x 32(nc) x 4(b); chunked XCD swizzle
  int id = blockIdx.x;
  int swz = (id & 7) * 64 + (id >> 3);
  int ig = swz & 3, nc = (swz >> 2) & 31, b = swz >> 7;
  int i0 = ig * 128;
  const u16* Bt = ctx_bt + (size_t)b * NTOK * CDIM;

  __shared__ __align__(16) u16 smem[32768];   // 64 KiB -> 2 blocks/CU
  // staging buf p (p=0,1): A at p*8192, B at p*8192+4096 (each 128 rows x 32 k)
  u16* Ek = smem + 16384;    // [32K,64K) expK tile, dedicated
  u16* Vt = smem;            // [0,32K)   V tile, aliases both staging bufs

  int tid = threadIdx.x, wave = tid >> 6, lane = tid & 63;
  int wm = (wave >> 1) * 64, wn = (wave & 1) * 64;
  int quad = lane >> 4, l16 = lane & 15;
  int sr = lane >> 2, sc = (lane & 3) * 8;      // staging: 16 rows x 32 cols/chunk

  int hl = wave >> 1, dblk = (wave & 1) * 32;   // phase-2: wave -> (head, d-half)

  u16x8 ov;
#pragma unroll
  for (int t = 0; t < 8; t++) ov[t] = 0x3f80;   // bf16 1.0
  const bf16x8 ones = __builtin_bit_cast(bf16x8, ov);

  f32x4 acc_cm[2][4];
  f32x4 accS[2];
#pragma unroll
  for (int i = 0; i < 2; i++) {
    accS[i] = (f32x4)(0.0f);
#pragma unroll
    for (int j = 0; j < 4; j++) acc_cm[i][j] = (f32x4)(0.0f);
  }

  // stage step (kv, k-slice ks) into buf p. 16 chunks of 16rows x 32cols; 4/wave.
  auto stage = [&](int p, int kv, int ks, int n0) {
    int k0 = ks * 32;
    const u16* Asrc = kv ? Wvt : Wkt;
#pragma unroll
    for (int j = 0; j < 4; j++) {
      int c = wave * 4 + j;            // 0..15
      if (c < 8) {
        int row = c * 16 + sr;
        async_ld16(&Asrc[(size_t)(i0 + row) * CDIM + k0 + sc], &smem[p * 8192 + c * 512]);
      } else {
        int cb = c - 8, row = cb * 16 + sr;
        async_ld16(&Bt[(size_t)(n0 + row) * CDIM + k0 + sc], &smem[p * 8192 + 4096 + cb * 512]);
      }
    }
  };

  for (int nt = 0; nt < 4; nt++) {
    int n0 = nc * 512 + nt * 128;
    __syncthreads();                   // phase-2 reads of Vt/Ek done (or block start)
    stage(0, 0, 0, n0);
    __syncthreads();                   // buf0 ready (implicit vmcnt(0) drain)

    f32x4 acc[4][4];
#pragma unroll
    for (int i = 0; i < 4; i++)
#pragma unroll
      for (int j = 0; j < 4; j++) acc[i][j] = (f32x4)(0.0f);

#pragma unroll 2
    for (int s = 0; s < 16; s++) {     // s>>3 = kv, s&7 = k-slice
      int p = s & 1;
      if (s < 15) { int s1 = s + 1; stage(p ^ 1, s1 >> 3, s1 & 7, n0); }
      const u16* As = &smem[p * 8192];
      const u16* Bs = &smem[p * 8192 + 4096];
      bf16x8 af[4], bfr[4];
#pragma unroll
      for (int m = 0; m < 4; m++)
        af[m] = __builtin_bit_cast(bf16x8, *(const u16x8*)&As[(wm + m * 16 + l16) * 32 + quad * 8]);
#pragma unroll
      for (int e = 0; e < 4; e++)
        bfr[e] = __builtin_bit_cast(bf16x8, *(const u16x8*)&Bs[(wn + e * 16 + l16) * 32 + quad * 8]);
      // swapped operands: lane holds 4 consecutive n per frag
#pragma unroll
      for (int e = 0; e < 4; e++)
#pragma unroll
        for (int m = 0; m < 4; m++)
          acc[e][m] = __builtin_amdgcn_mfma_f32_16x16x32_bf16(bfr[e], af[m], acc[e][m], 0, 0, 0);

      if (s == 7) {
        // K-GEMM complete: write exp(K) to dedicated Ek (XOR-swz), reset acc for V
#pragma unroll
        for (int e = 0; e < 4; e++) {
          int nl0 = wn + e * 16 + quad * 4;
#pragma unroll
          for (int m = 0; m < 4; m++) {
            int row = wm + m * 16 + l16;
            u16x4 ok;
#pragma unroll
            for (int r = 0; r < 4; r++) ok[r] = f2b(__expf(acc[e][m][r]));
            unsigned byt = (unsigned)(row * 256 + nl0 * 2) ^ ((unsigned)(row & 7) << 4);
            *(u16x4*)((char*)Ek + byt) = ok;
            acc[e][m] = (f32x4)(0.0f);
          }
        }
      }
      __syncthreads();                 // next buf ready + buf-reuse safe
    }
    // acc holds V tile; staging fully drained & read -> Vt may alias it
#pragma unroll
    for (int e = 0; e < 4; e++) {
      int nl0 = wn + e * 16 + quad * 4;
#pragma unroll
      for (int m = 0; m < 4; m++) {
        int row = wm + m * 16 + l16;
        u16x4 ovv;
#pragma unroll
        for (int r = 0; r < 4; r++) ovv[r] = f2b(acc[e][m][r]);
        unsigned byt = (unsigned)(row * 256 + nl0 * 2) ^ ((unsigned)(row & 7) << 4);
        *(u16x4*)((char*)Vt + byt) = ovv;
      }
    }
    __syncthreads();                   // Ek/Vt visible to all waves
    // phase 2: per wave (hl, dblk): acc_cm[m2][e2] += Ek_row · Vt_row over 128 n
#pragma unroll
    for (int kk = 0; kk < 128; kk += 32) {
      int ko = kk + quad * 8;
      bf16x8 ea[2], vb[4];
#pragma unroll
      for (int m2 = 0; m2 < 2; m2++) {
        int row = hl * 64 + dblk + m2 * 16 + l16;
        unsigned byt = (unsigned)(row * 256 + ko * 2) ^ ((unsigned)(row & 7) << 4);
        ea[m2] = __builtin_bit_cast(bf16x8, *(const u16x8*)((char*)Ek + byt));
      }
#pragma unroll
      for (int e2 = 0; e2 < 4; e2++) {
        int row = hl * 64 + e2 * 16 + l16;
        unsigned byt = (unsigned)(row * 256 + ko * 2) ^ ((unsigned)(row & 7) << 4);
        vb[e2] = __builtin_bit_cast(bf16x8, *(const u16x8*)((char*)Vt + byt));
      }
#pragma unroll
      for (int m2 = 0; m2 < 2; m2++) {
        accS[m2] = __builtin_amdgcn_mfma_f32_16x16x32_bf16(ea[m2], ones, accS[m2], 0, 0, 0);
#pragma unroll
        for (int e2 = 0; e2 < 4; e2++)
          acc_cm[m2][e2] = __builtin_amdgcn_mfma_f32_16x16x32_bf16(ea[m2], vb[e2], acc_cm[m2][e2], 0, 0, 0);
      }
    }
    // next nt's first __syncthreads protects Ek/Vt vs staging overwrite
  }
  // epilogue: waves own disjoint (h, d-half) -> no intra-block contention
  int h = ig * 2 + hl;
  float* cmp = cm + (size_t)(b * 8 + h) * 64 * 64;
#pragma unroll
  for (int m2 = 0; m2 < 2; m2++)
#pragma unroll
    for (int e2 = 0; e2 < 4; e2++)
#pragma unroll
      for (int r = 0; r < 4; r++) {
        int d = dblk + m2 * 16 + quad * 4 + r;
        int e = e2 * 16 + l16;
        atomicAdd(&cmp[d * 64 + e], acc_cm[m2][e2][r]);
      }
  if (l16 == 0) {
#pragma unroll
    for (int m2 = 0; m2 < 2; m2++)
#pragma unroll
      for (int r = 0; r < 4; r++) {
        int d = dblk + m2 * 16 + quad * 4 + r;
        atomicAdd(&ksum[(size_t)b * INNERD + h * 64 + d], accS[m2][r]);
      }
  }
}

// ---------------- weff[b][i=h*64+d][c] = (sum_e cm[d][e]*Wo[h*64+e][c])/ksum ---
__global__ __launch_bounds__(256) void weff_k(
    const float* __restrict__ cm, const float* __restrict__ Wo,
    const float* __restrict__ ksum, float* __restrict__ weff) {
  int bi = blockIdx.x;            // 0..2047
  int b = bi >> 9, i = bi & 511, h = i >> 6, d = i & 63;
  const float* cmr = cm + ((size_t)(b * 8 + h) * 64 + d) * 64;
  __shared__ float cs[64];
  if (threadIdx.x < 64) cs[threadIdx.x] = cmr[threadIdx.x];
  __syncthreads();
  float inv = 1.0f / ksum[(size_t)b * INNERD + i];
  int c = threadIdx.x;
  float s = 0.0f;
#pragma unroll 8
  for (int e = 0; e < 64; e++) s += cs[e] * Wo[(size_t)(h * 64 + e) * CDIM + c];
  weff[(size_t)bi * CDIM + c] = s * inv;
}

// ---------------- Gt[b][c][c'] = sum_i weff[b][i][c] * Wq_t[i][c']  (bf16) -----
__global__ __launch_bounds__(256) void gt_k(
    const float* __restrict__ weff, const u16* __restrict__ Wq_t, u16* __restrict__ Gt) {
  int bc = blockIdx.x;            // 0..1023
  int b = bc >> 8, c = bc & 255;
  __shared__ float ws[512];
  for (int j = threadIdx.x; j < 512; j += 256)
    ws[j] = weff[((size_t)b * 512 + j) * CDIM + c];
  __syncthreads();
  int cp = threadIdx.x;
  float s = 0.0f;
#pragma unroll 8
  for (int i = 0; i < 512; i++) s += ws[i] * b2f(Wq_t[(size_t)i * CDIM + cp]);
  Gt[(size_t)bc * CDIM + cp] = f2b(s);
}

// ---------------- final: out[b][c][n] = x + bo[c] + sum_c' Gt[c][c'] x_bt[n][c']
// Same prefetch ladder (BK=32, 8 steps); f32x4 residual epilogue.
__global__ __launch_bounds__(256) void final_gemm(
    const u16* __restrict__ Gt, const u16* __restrict__ x_bt,
    const float* __restrict__ x, const float* __restrict__ bo,
    float* __restrict__ out) {
  // flattened grid 1024 = 2(x) * 128(y) * 4(z); chunked XCD swizzle
  int id = blockIdx.x;
  int swz = (id & 7) * 128 + (id >> 3);
  int bx = swz & 1, by = (swz >> 1) & 127, b = swz >> 8;
  const u16* A  = Gt + (size_t)b * CDIM * CDIM;
  const u16* Bt = x_bt + (size_t)b * NTOK * CDIM;
  const float* xb = x + (size_t)b * CDIM * NTOK;
  float* ob = out + (size_t)b * CDIM * NTOK;
  int i0 = bx * 128;
  int n0 = by * 128;

  __shared__ __align__(16) u16 smem2[16384];   // 32 KiB: 2 bufs x (A 4K + B 4K u16)

  int tid = threadIdx.x;
  int wave = tid >> 6, lane = tid & 63;
  int wm = (wave >> 1) * 64, wn = (wave & 1) * 64;
  int quad = lane >> 4, l16 = lane & 15;
  int sr = lane >> 2, sc = (lane & 3) * 8;

  auto stage = [&](int p, int ks) {
    int k0 = ks * 32;
#pragma unroll
    for (int j = 0; j < 4; j++) {
      int c = wave * 4 + j;
      if (c < 8) {
        int row = c * 16 + sr;
        async_ld16(&A[(size_t)(i0 + row) * CDIM + k0 + sc], &smem2[p * 8192 + c * 512]);
      } else {
        int cb = c - 8, row = cb * 16 + sr;
        async_ld16(&Bt[(size_t)(n0 + row) * CDIM + k0 + sc], &smem2[p * 8192 + 4096 + cb * 512]);
      }
    }
  };

  f32x4 acc[4][4];   // [e:n-frag][m:c-frag]
#pragma unroll
  for (int i = 0; i < 4; i++)
#pragma unroll
    for (int j = 0; j < 4; j++) acc[i][j] = (f32x4)(0.0f);

  stage(0, 0);
  __syncthreads();
#pragma unroll 2
  for (int s = 0; s < 8; s++) {
    int p = s & 1;
    if (s < 7) stage(p ^ 1, s + 1);
    const u16* As = &smem2[p * 8192];
    const u16* Bs = &smem2[p * 8192 + 4096];
    bf16x8 af[4], bfr[4];
#pragma unroll
    for (int m = 0; m < 4; m++)
      af[m] = __builtin_bit_cast(bf16x8, *(const u16x8*)&As[(wm + m * 16 + l16) * 32 + quad * 8]);
#pragma unroll
    for (int e = 0; e < 4; e++)
      bfr[e] = __builtin_bit_cast(bf16x8, *(const u16x8*)&Bs[(wn + e * 16 + l16) * 32 + quad * 8]);
#pragma unroll
    for (int e = 0; e < 4; e++)
#pragma unroll
      for (int m = 0; m < 4; m++)
        acc[e][m] = __builtin_amdgcn_mfma_f32_16x16x32_bf16(bfr[e], af[m], acc[e][m], 0, 0, 0);
    if (s < 7) __syncthreads();
  }
  // lane's acc[e][m][r]: c = i0+wm+m*16+l16, n = n0+wn+e*16+quad*4+r
#pragma unroll
  for (int e = 0; e < 4; e++) {
    int nb = n0 + wn + e * 16 + quad * 4;
#pragma unroll
    for (int m = 0; m < 4; m++) {
      int c = i0 + wm + m * 16 + l16;
      f32x4 xv = *(const f32x4*)&xb[(size_t)c * NTOK + nb];
      f32x4 r;
      float bc = bo[c];
#pragma unroll
      for (int t = 0; t < 4; t++) r[t] = acc[e][m][t] + xv[t] + bc;
      *(f32x4*)&ob[(size_t)c * NTOK + nb] = r;
    }
  }
}

extern "C" void kernel_launch(void* const* d_in, const int* in_sizes, int n_in,
                              void* d_out, int out_size, void* d_ws, size_t ws_size,
                              hipStream_t stream) {
  const float* x   = (const float*)d_in[0];
  const float* ctx = (const float*)d_in[1];
  const float* Wq  = (const float*)d_in[2];
  const float* Wk  = (const float*)d_in[3];
  const float* Wv  = (const float*)d_in[4];
  const float* Wo  = (const float*)d_in[5];
  const float* bo  = (const float*)d_in[6];
  float* out = (float*)d_out;

  char* ws = (char*)d_ws;
  u16* ctx_bt = (u16*)ws;  ws += (size_t)BATCH * NTOK * CDIM * 2;     // 32 MiB
  u16* x_bt   = (u16*)ws;  ws += (size_t)BATCH * NTOK * CDIM * 2;     // 32 MiB
  u16* Wq_t   = (u16*)ws;  ws += (size_t)INNERD * CDIM * 2;
  u16* Wk_t   = (u16*)ws;  ws += (size_t)INNERD * CDIM * 2;
  u16* Wv_t   = (u16*)ws;  ws += (size_t)INNERD * CDIM * 2;
  float* cm   = (float*)ws; ws += (size_t)BATCH * 8 * 64 * 64 * 4;    // 512 KiB
  float* ksum = (float*)ws; ws += (size_t)BATCH * INNERD * 4;         // 8 KiB (contiguous after cm)
  float* weff = (float*)ws; ws += (size_t)BATCH * INNERD * CDIM * 4;  // 2 MiB
  u16* Gt     = (u16*)ws;  ws += (size_t)BATCH * CDIM * CDIM * 2;

  prep<<<dim3(17288), 256, 0, stream>>>(x, ctx, Wq, Wk, Wv, x_bt, ctx_bt,
                                        Wq_t, Wk_t, Wv_t, cm /* zero cm+ksum */);
  proj_ctx<<<dim3(512), 256, 0, stream>>>(Wk_t, Wv_t, ctx_bt, cm, ksum);
  weff_k<<<BATCH * INNERD, 256, 0, stream>>>(cm, Wo, ksum, weff);
  gt_k<<<BATCH * CDIM, 256, 0, stream>>>(weff, Wq_t, Gt);
  final_gemm<<<dim3(1024), 256, 0, stream>>>(Gt, x_bt, x, bo, out);
}